// Round 1
// baseline (2590.828 us; speedup 1.0000x reference)
//
#include <hip/hip_runtime.h>
#include <hip/hip_bf16.h>
#include <math.h>

#define S_DIM 16
#define O_DIM 8
#define J_DIM 32
#define B_DIM 4096
#define HID 240
#define OHID 512

// ws layout (float offsets)
#define WS_XPRED   0                                  // [B,16]
#define WS_INNO    (WS_XPRED + B_DIM*S_DIM)           // [B,8]
#define WS_FEATS   (WS_INNO + B_DIM*O_DIM)            // [B,48]
#define WS_XIN0    (WS_FEATS + B_DIM*48)              // [B,240]
#define WS_GH      (WS_XIN0 + B_DIM*HID)              // [960]: add[720], mul[240]
#define WS_WIHT    (WS_GH + 960)                      // [240,720]
#define WS_WO1T    (WS_WIHT + 720*HID)                // [240,512]
#define WS_WO2T    (WS_WO1T + OHID*HID)               // [512,128]

// out layout (float offsets)
#define OUT_X      0
#define OUT_P      (B_DIM*S_DIM)                      // 65536
#define OUT_REG    (2*B_DIM*S_DIM)                    // 131072
#define OUT_ENS    (2*B_DIM*S_DIM + 1)                // 131073

// ---------------------------------------------------------------------------
// aux: transpose weights + gh = h_init @ W_hh^T + b_hh (with b_ih folding)
// ---------------------------------------------------------------------------
__global__ void k_aux(const float* __restrict__ W_ih, const float* __restrict__ W_hh,
                      const float* __restrict__ b_ih, const float* __restrict__ b_hh,
                      const float* __restrict__ h_init,
                      const float* __restrict__ W_o1, const float* __restrict__ W_o2,
                      float* __restrict__ WihT, float* __restrict__ Wo1T,
                      float* __restrict__ Wo2T, float* __restrict__ ghb)
{
    int t = blockIdx.x * 256 + threadIdx.x;
    if (t < 720*240) {
        int g = t / 240, k = t - g*240;
        WihT[k*720 + g] = W_ih[t];
    } else if (t < 720*240 + 512*240) {
        int u = t - 720*240;
        int g = u / 240, k = u - g*240;
        Wo1T[k*512 + g] = W_o1[u];
    } else if (t < 720*240 + 512*240 + 128*512) {
        int u = t - 720*240 - 512*240;
        int g = u / 512, k = u - g*512;
        Wo2T[k*128 + g] = W_o2[u];
    }
    if (t < 720) {
        float a = b_hh[t];
        const float* wr = W_hh + t*240;
        for (int k = 0; k < 240; k++) a = fmaf(h_init[k], wr[k], a);
        if (t < 480) {
            ghb[t] = b_ih[t] + a;            // r/z gates: bias fully folded
        } else {
            ghb[t] = b_ih[t];                // n gate: additive part (b_ih only)
            ghb[t + 240] = a;                // n gate: part multiplied by r
        }
    }
}

// ---------------------------------------------------------------------------
// pre_a: Kalman prefix per b -> x_pred, innovation, feats
// ---------------------------------------------------------------------------
__global__ void k_pre_a(const float* __restrict__ y, const float* __restrict__ xprev,
                        const float* __restrict__ F, const float* __restrict__ Hm,
                        float* __restrict__ x_pred, float* __restrict__ inno,
                        float* __restrict__ feats)
{
    __shared__ float sF[256], sH[128];
    int tid = threadIdx.x;
    if (tid < 256) sF[tid] = F[tid];
    if (tid < 128) sH[tid] = Hm[tid];
    __syncthreads();
    int b = blockIdx.x * 256 + tid;
    float xf[16], xp[16], inn[8];
    #pragma unroll
    for (int s = 0; s < 16; s++) xf[s] = xprev[b*16 + s];
    #pragma unroll
    for (int s = 0; s < 16; s++) {
        float a = 0.f;
        #pragma unroll
        for (int k = 0; k < 16; k++) a = fmaf(xf[k], sF[s*16 + k], a);
        xp[s] = a;
    }
    #pragma unroll
    for (int o = 0; o < 8; o++) {
        float a = 0.f;
        #pragma unroll
        for (int k = 0; k < 16; k++) a = fmaf(xp[k], sH[o*16 + k], a);
        inn[o] = y[b*8 + o] - a;
    }
    #pragma unroll
    for (int s = 0; s < 16; s++) x_pred[b*16 + s] = xp[s];
    #pragma unroll
    for (int o = 0; o < 8; o++) inno[b*8 + o] = inn[o];
    float* fb = feats + b*48;
    #pragma unroll
    for (int s = 0; s < 16; s++) fb[s] = xf[s] - xp[s];       // state_inno
    #pragma unroll
    for (int o = 0; o < 8; o++) fb[16 + o] = inn[o];          // innovation
    #pragma unroll
    for (int s = 0; s < 16; s++) fb[24 + s] = 0.f;            // diff_state (first step)
    #pragma unroll
    for (int o = 0; o < 8; o++) fb[40 + o] = inn[o];          // diff_obs
}

// ---------------------------------------------------------------------------
// pre_b: x_in0 = relu(feats @ W_fc^T + b_fc), thread per (b,h)
// ---------------------------------------------------------------------------
__global__ void k_pre_b(const float* __restrict__ feats, const float* __restrict__ Wfc,
                        const float* __restrict__ bfc, float* __restrict__ x_in0)
{
    int t = blockIdx.x * 256 + threadIdx.x;
    int b = t / 240, h = t - b*240;
    const float* fb = feats + b*48;
    const float* wr = Wfc + h*48;
    float a = bfc[h];
    #pragma unroll
    for (int k = 0; k < 48; k += 4) {
        const float4 f4 = *(const float4*)&fb[k];
        const float4 w4 = *(const float4*)&wr[k];
        a = fmaf(f4.x, w4.x, fmaf(f4.y, w4.y, fmaf(f4.z, w4.z, fmaf(f4.w, w4.w, a))));
    }
    x_in0[t] = fmaxf(a, 0.f);
}

// ---------------------------------------------------------------------------
// main: fused dropout -> GRU -> out1 -> K -> correction -> ensemble
// 16 (j,b)-rows per block, 256 threads. LDS ~64KB -> 2 blocks/CU.
// ---------------------------------------------------------------------------
#define O1_STRIDE 516   // 512 + 4 pad: kills 4-way bank conflict in phase 3

__global__ __launch_bounds__(256, 2) void k_main(
    const float* __restrict__ x_in0, const float* __restrict__ u1,
    const float* __restrict__ u2,
    const float* __restrict__ WihT, const float* __restrict__ ghb,
    const float* __restrict__ h_init,
    const float* __restrict__ Wo1T, const float* __restrict__ b_out1,
    const float* __restrict__ Wo2T, const float* __restrict__ b_out2,
    const float* __restrict__ x_pred, const float* __restrict__ inno,
    float* __restrict__ ens)
{
    __shared__ float Xs[16*240];
    __shared__ float Hs[16*240];
    __shared__ float O1s[16*O1_STRIDE];
    __shared__ float XPs[16*16];
    __shared__ float InnoS[16*8];

    const int tid = threadIdx.x;
    const int grow0 = blockIdx.x * 16;
    const int j  = grow0 >> 12;      // all 16 rows share j (16 | 4096)
    const int b0 = grow0 & 4095;

    // ---- phase 0: stage masked x_in, x_pred tile, innovation tile ----
    for (int idx = tid; idx < 16*240; idx += 256) {
        int i = idx / 240, h = idx - i*240;
        int b = b0 + i;
        float v = x_in0[b*240 + h];
        float u = u1[((size_t)j*B_DIM + b)*240 + h];
        Xs[idx] = (u > 0.5f) ? 2.0f*v : 0.0f;      // mask1/(1-P1)
    }
    { int i = tid >> 4, s = tid & 15; XPs[tid] = x_pred[(b0+i)*16 + s]; }
    if (tid < 128) { int i = tid >> 3, o = tid & 7; InnoS[tid] = inno[(b0+i)*8 + o]; }
    __syncthreads();

    // ---- phase 1: GRU -> Hs. thread h computes h_new[h] for all 16 rows ----
    if (tid < 240) {
        const int h = tid;
        float ar[16], az[16], an[16];
        #pragma unroll
        for (int i = 0; i < 16; i++) { ar[i] = 0.f; az[i] = 0.f; an[i] = 0.f; }
        for (int k = 0; k < 240; k += 4) {
            float wr[4], wz[4], wn[4];
            #pragma unroll
            for (int q = 0; q < 4; q++) {
                const float* wp = WihT + (size_t)(k+q)*720 + h;
                wr[q] = wp[0]; wz[q] = wp[240]; wn[q] = wp[480];
            }
            #pragma unroll
            for (int i = 0; i < 16; i++) {
                const float4 x = *(const float4*)&Xs[i*240 + k];   // LDS broadcast
                ar[i] = fmaf(x.x,wr[0],fmaf(x.y,wr[1],fmaf(x.z,wr[2],fmaf(x.w,wr[3],ar[i]))));
                az[i] = fmaf(x.x,wz[0],fmaf(x.y,wz[1],fmaf(x.z,wz[2],fmaf(x.w,wz[3],az[i]))));
                an[i] = fmaf(x.x,wn[0],fmaf(x.y,wn[1],fmaf(x.z,wn[2],fmaf(x.w,wn[3],an[i]))));
            }
        }
        const float add_r = ghb[h], add_z = ghb[240+h];
        const float add_n = ghb[480+h], mul_n = ghb[720+h];
        const float hi = h_init[h];
        #pragma unroll
        for (int i = 0; i < 16; i++) {
            float r = 1.0f/(1.0f + expf(-(ar[i] + add_r)));
            float z = 1.0f/(1.0f + expf(-(az[i] + add_z)));
            float n = tanhf(an[i] + add_n + r*mul_n);
            Hs[i*240 + h] = (1.0f - z)*n + z*hi;
        }
    }
    __syncthreads();

    // ---- phase 2: o1 = relu(h_new@W_out1^T+b)*mask2 -> O1s. thread: oc, oc+256 ----
    {
        const int oc0 = tid, oc1 = tid + 256;
        float a0[16], a1[16];
        #pragma unroll
        for (int i = 0; i < 16; i++) { a0[i] = 0.f; a1[i] = 0.f; }
        for (int k = 0; k < 240; k += 4) {
            float w0[4], w1[4];
            #pragma unroll
            for (int q = 0; q < 4; q++) {
                const float* wp = Wo1T + (size_t)(k+q)*512;
                w0[q] = wp[oc0]; w1[q] = wp[oc1];
            }
            #pragma unroll
            for (int i = 0; i < 16; i++) {
                const float4 x = *(const float4*)&Hs[i*240 + k];   // LDS broadcast
                a0[i] = fmaf(x.x,w0[0],fmaf(x.y,w0[1],fmaf(x.z,w0[2],fmaf(x.w,w0[3],a0[i]))));
                a1[i] = fmaf(x.x,w1[0],fmaf(x.y,w1[1],fmaf(x.z,w1[2],fmaf(x.w,w1[3],a1[i]))));
            }
        }
        const float bb0 = b_out1[oc0], bb1 = b_out1[oc1];
        const float inv35 = 1.0f/0.35f;
        #pragma unroll
        for (int i = 0; i < 16; i++) {
            const int b = b0 + i;
            const size_t ub = ((size_t)j*B_DIM + b)*512;
            float m0 = (u2[ub + oc0] > 0.65f) ? inv35 : 0.0f;
            float m1 = (u2[ub + oc1] > 0.65f) ? inv35 : 0.0f;
            O1s[i*O1_STRIDE + oc0] = fmaxf(a0[i] + bb0, 0.f) * m0;
            O1s[i*O1_STRIDE + oc1] = fmaxf(a1[i] + bb1, 0.f) * m1;
        }
    }
    __syncthreads();

    // ---- phase 3: K = o1@W_out2^T+b, corr = K·inno, ensemble ----
    {
        const int i = tid >> 4, s = tid & 15;
        float acc[8];
        #pragma unroll
        for (int o = 0; o < 8; o++) acc[o] = b_out2[s*8 + o];
        for (int k = 0; k < 512; k += 4) {
            const float4 x = *(const float4*)&O1s[i*O1_STRIDE + k];
            #pragma unroll
            for (int q = 0; q < 4; q++) {
                const float xv = (q==0) ? x.x : (q==1) ? x.y : (q==2) ? x.z : x.w;
                const float4 wA = *(const float4*)&Wo2T[(size_t)(k+q)*128 + s*8];
                const float4 wB = *(const float4*)&Wo2T[(size_t)(k+q)*128 + s*8 + 4];
                acc[0] = fmaf(xv, wA.x, acc[0]);
                acc[1] = fmaf(xv, wA.y, acc[1]);
                acc[2] = fmaf(xv, wA.z, acc[2]);
                acc[3] = fmaf(xv, wA.w, acc[3]);
                acc[4] = fmaf(xv, wB.x, acc[4]);
                acc[5] = fmaf(xv, wB.y, acc[5]);
                acc[6] = fmaf(xv, wB.z, acc[6]);
                acc[7] = fmaf(xv, wB.w, acc[7]);
            }
        }
        float c = 0.f;
        #pragma unroll
        for (int o = 0; o < 8; o++) c += acc[o] * InnoS[i*8 + o];
        ens[((size_t)(b0+i)*J_DIM + j)*16 + s] = XPs[i*16 + s] + c;
    }
}

// ---------------------------------------------------------------------------
// final: mean/var(ddof=1) over J per (b,s), plus reg scalar
// ---------------------------------------------------------------------------
__global__ void k_final(const float* __restrict__ ens, float* __restrict__ out)
{
    int t = blockIdx.x * 256 + threadIdx.x;   // 65536 = B*S
    int b = t >> 4, s = t & 15;
    float v[32];
    #pragma unroll
    for (int jj = 0; jj < 32; jj++) v[jj] = ens[((size_t)b*32 + jj)*16 + s];
    float m = 0.f;
    #pragma unroll
    for (int jj = 0; jj < 32; jj++) m += v[jj];
    m *= (1.0f/32.0f);
    float var = 0.f;
    #pragma unroll
    for (int jj = 0; jj < 32; jj++) { float d = v[jj] - m; var = fmaf(d, d, var); }
    var *= (1.0f/31.0f);
    out[OUT_X + t] = m;
    out[OUT_P + t] = var;
    if (t == 0) out[OUT_REG] = 1.3405938195945778f;  // ln2 + H(0.65)
}

// ---------------------------------------------------------------------------
extern "C" void kernel_launch(void* const* d_in, const int* in_sizes, int n_in,
                              void* d_out, int out_size, void* d_ws, size_t ws_size,
                              hipStream_t stream)
{
    (void)in_sizes; (void)n_in; (void)out_size; (void)ws_size;
    const float* y_t    = (const float*)d_in[0];
    const float* xprev  = (const float*)d_in[1];
    const float* F      = (const float*)d_in[2];
    const float* Hm     = (const float*)d_in[3];
    const float* Wfc    = (const float*)d_in[4];
    const float* bfc    = (const float*)d_in[5];
    const float* W_ih   = (const float*)d_in[6];
    const float* W_hh   = (const float*)d_in[7];
    const float* b_ih   = (const float*)d_in[8];
    const float* b_hh   = (const float*)d_in[9];
    const float* W_o1   = (const float*)d_in[10];
    const float* b_o1   = (const float*)d_in[11];
    const float* W_o2   = (const float*)d_in[12];
    const float* b_o2   = (const float*)d_in[13];
    const float* h_init = (const float*)d_in[14];
    const float* u1     = (const float*)d_in[15];
    const float* u2     = (const float*)d_in[16];

    float* out = (float*)d_out;
    float* ws  = (float*)d_ws;
    float* x_pred = ws + WS_XPRED;
    float* inno   = ws + WS_INNO;
    float* feats  = ws + WS_FEATS;
    float* x_in0  = ws + WS_XIN0;
    float* ghb    = ws + WS_GH;
    float* WihT   = ws + WS_WIHT;
    float* Wo1T   = ws + WS_WO1T;
    float* Wo2T   = ws + WS_WO2T;
    float* ens    = out + OUT_ENS;

    k_aux<<<dim3(1412), dim3(256), 0, stream>>>(W_ih, W_hh, b_ih, b_hh, h_init,
                                                W_o1, W_o2, WihT, Wo1T, Wo2T, ghb);
    k_pre_a<<<dim3(16), dim3(256), 0, stream>>>(y_t, xprev, F, Hm, x_pred, inno, feats);
    k_pre_b<<<dim3(3840), dim3(256), 0, stream>>>(feats, Wfc, bfc, x_in0);
    k_main<<<dim3(8192), dim3(256), 0, stream>>>(x_in0, u1, u2, WihT, ghb, h_init,
                                                 Wo1T, b_o1, Wo2T, b_o2,
                                                 x_pred, inno, ens);
    k_final<<<dim3(256), dim3(256), 0, stream>>>(ens, out);
}

// Round 2
// 873.329 us; speedup vs baseline: 2.9666x; 2.9666x over previous
//
#include <hip/hip_runtime.h>
#include <hip/hip_bf16.h>
#include <math.h>

#define S_DIM 16
#define O_DIM 8
#define J_DIM 32
#define B_DIM 4096
#define HID 240
#define OHID 512

typedef __attribute__((ext_vector_type(8))) short bf16x8;
typedef __attribute__((ext_vector_type(4))) float f32x4;
#define MFMA16(a,b,c) __builtin_amdgcn_mfma_f32_16x16x32_bf16((a),(b),(c),0,0,0)

// ws layout (float offsets for fp32 part)
#define WS_XPRED   0                                  // [B,16]
#define WS_INNO    (WS_XPRED + B_DIM*S_DIM)           // [B,8]
#define WS_FEATS   (WS_INNO + B_DIM*O_DIM)            // [B,48]
#define WS_XIN0    (WS_FEATS + B_DIM*48)              // [B,240]
#define WS_GH      (WS_XIN0 + B_DIM*HID)              // [960]
#define WS_WB_OFF  ((WS_GH + 960) * 4)                // byte offset: bf16 weights
// bf16 weights: Wihb[768][256], Wo1b[512][256], Wo2b[128][512]

// out layout (float offsets)
#define OUT_X      0
#define OUT_P      (B_DIM*S_DIM)                      // 65536
#define OUT_REG    (2*B_DIM*S_DIM)                    // 131072
#define OUT_ENS    (2*B_DIM*S_DIM + 1)                // 131073

// ---------------------------------------------------------------------------
// aux: cast weights to bf16 (K-padded) + GRU gh precompute
// ---------------------------------------------------------------------------
__global__ void k_aux(const float* __restrict__ W_ih, const float* __restrict__ W_hh,
                      const float* __restrict__ b_ih, const float* __restrict__ b_hh,
                      const float* __restrict__ h_init,
                      const float* __restrict__ W_o1, const float* __restrict__ W_o2,
                      __hip_bfloat16* __restrict__ Wihb, __hip_bfloat16* __restrict__ Wo1b,
                      __hip_bfloat16* __restrict__ Wo2b, float* __restrict__ ghb)
{
    int t = blockIdx.x * 256 + threadIdx.x;
    if (t < 768*256) {
        int n = t >> 8, k = t & 255;
        float v = (n < 720 && k < 240) ? W_ih[n*240 + k] : 0.0f;
        Wihb[t] = __float2bfloat16(v);
    } else if (t < 768*256 + 512*256) {
        int u = t - 768*256;
        int n = u >> 8, k = u & 255;
        float v = (k < 240) ? W_o1[n*240 + k] : 0.0f;
        Wo1b[u] = __float2bfloat16(v);
    } else if (t < 768*256 + 512*256 + 128*512) {
        int u = t - 768*256 - 512*256;
        Wo2b[u] = __float2bfloat16(W_o2[u]);
    }
    if (t < 720) {
        float a = b_hh[t];
        const float* wr = W_hh + t*240;
        for (int k = 0; k < 240; k++) a = fmaf(h_init[k], wr[k], a);
        if (t < 480) {
            ghb[t] = b_ih[t] + a;            // r/z gates: bias fully folded
        } else {
            ghb[t] = b_ih[t];                // n gate: additive part
            ghb[t + 240] = a;                // n gate: part multiplied by r
        }
    }
}

// ---------------------------------------------------------------------------
// pre_a: Kalman prefix per b -> x_pred, innovation, feats
// ---------------------------------------------------------------------------
__global__ void k_pre_a(const float* __restrict__ y, const float* __restrict__ xprev,
                        const float* __restrict__ F, const float* __restrict__ Hm,
                        float* __restrict__ x_pred, float* __restrict__ inno,
                        float* __restrict__ feats)
{
    __shared__ float sF[256], sH[128];
    int tid = threadIdx.x;
    sF[tid] = F[tid];
    if (tid < 128) sH[tid] = Hm[tid];
    __syncthreads();
    int b = blockIdx.x * 256 + tid;
    float xf[16], xp[16], inn[8];
    #pragma unroll
    for (int s = 0; s < 16; s++) xf[s] = xprev[b*16 + s];
    #pragma unroll
    for (int s = 0; s < 16; s++) {
        float a = 0.f;
        #pragma unroll
        for (int k = 0; k < 16; k++) a = fmaf(xf[k], sF[s*16 + k], a);
        xp[s] = a;
    }
    #pragma unroll
    for (int o = 0; o < 8; o++) {
        float a = 0.f;
        #pragma unroll
        for (int k = 0; k < 16; k++) a = fmaf(xp[k], sH[o*16 + k], a);
        inn[o] = y[b*8 + o] - a;
    }
    #pragma unroll
    for (int s = 0; s < 16; s++) x_pred[b*16 + s] = xp[s];
    #pragma unroll
    for (int o = 0; o < 8; o++) inno[b*8 + o] = inn[o];
    float* fb = feats + b*48;
    #pragma unroll
    for (int s = 0; s < 16; s++) fb[s] = xf[s] - xp[s];
    #pragma unroll
    for (int o = 0; o < 8; o++) fb[16 + o] = inn[o];
    #pragma unroll
    for (int s = 0; s < 16; s++) fb[24 + s] = 0.f;
    #pragma unroll
    for (int o = 0; o < 8; o++) fb[40 + o] = inn[o];
}

// ---------------------------------------------------------------------------
// pre_b: x_in0 = relu(feats @ W_fc^T + b_fc)
// ---------------------------------------------------------------------------
__global__ void k_pre_b(const float* __restrict__ feats, const float* __restrict__ Wfc,
                        const float* __restrict__ bfc, float* __restrict__ x_in0)
{
    int t = blockIdx.x * 256 + threadIdx.x;
    int b = t / 240, h = t - b*240;
    const float* fb = feats + b*48;
    const float* wr = Wfc + h*48;
    float a = bfc[h];
    #pragma unroll
    for (int k = 0; k < 48; k += 4) {
        const float4 f4 = *(const float4*)&fb[k];
        const float4 w4 = *(const float4*)&wr[k];
        a = fmaf(f4.x, w4.x, fmaf(f4.y, w4.y, fmaf(f4.z, w4.z, fmaf(f4.w, w4.w, a))));
    }
    x_in0[t] = fmaxf(a, 0.f);
}

// ---------------------------------------------------------------------------
// main: bf16 MFMA fused chain. 32 (j,b)-rows/block (2 M-tiles), 4 waves.
// LDS 52KB (O1s overlays dead Xs) -> 3 blocks/CU.
// ---------------------------------------------------------------------------
#define XS_STRIDE 264   // 240+24 pad bf16: 528B row -> banks offset 4/row (2-way, free)
#define O1_STRIDE 520   // 512+8 pad bf16: 1040B row -> same property

__global__ __launch_bounds__(256, 3) void k_main(
    const float* __restrict__ x_in0, const float* __restrict__ u1,
    const float* __restrict__ u2,
    const __hip_bfloat16* __restrict__ Wihb, const float* __restrict__ ghb,
    const float* __restrict__ h_init,
    const __hip_bfloat16* __restrict__ Wo1b, const float* __restrict__ b_out1,
    const __hip_bfloat16* __restrict__ Wo2b, const float* __restrict__ b_out2,
    const float* __restrict__ x_pred, const float* __restrict__ inno,
    float* __restrict__ ens)
{
    __shared__ __align__(16) char smem[53248];
    __hip_bfloat16* O1s = (__hip_bfloat16*)smem;            // [32][520], overlays Xs
    __hip_bfloat16* Xs  = (__hip_bfloat16*)smem;            // [32][264]
    __hip_bfloat16* Hs  = (__hip_bfloat16*)(smem + 33280);  // [32][264]
    float* XPs   = (float*)(smem + 50176);                  // [32][16]
    float* InnoS = (float*)(smem + 52224);                  // [32][8]

    const int tid = threadIdx.x;
    const int j  = blockIdx.x >> 7;          // 128 blocks per j
    const int b0 = (blockIdx.x & 127) << 5;  // 32 b-rows per block

    // ---- phase 0: stage masked bf16 X tile + pads + x_pred/inno tiles ----
    for (int idx = tid; idx < 32*240; idx += 256) {
        int i = idx / 240, h = idx - i*240;
        int b = b0 + i;
        float v = x_in0[b*240 + h];
        float u = u1[(j*B_DIM + b)*240 + h];
        Xs[i*XS_STRIDE + h] = __float2bfloat16((u > 0.5f) ? 2.0f*v : 0.0f);
    }
    for (int idx = tid; idx < 32*24; idx += 256) {
        int i = idx / 24, c = 240 + (idx - i*24);
        __hip_bfloat16 z = __float2bfloat16(0.0f);
        Xs[i*XS_STRIDE + c] = z;
        Hs[i*XS_STRIDE + c] = z;
    }
    XPs[tid]       = x_pred[(b0 + (tid >> 4))*16 + (tid & 15)];
    XPs[tid + 256] = x_pred[(b0 + ((tid + 256) >> 4))*16 + (tid & 15)];
    InnoS[tid]     = inno[(b0 + (tid >> 3))*8 + (tid & 7)];
    __syncthreads();

    const int wave = tid >> 6;
    const int l15  = tid & 15;
    const int quad = (tid >> 4) & 3;
    const f32x4 zero4 = {0.f, 0.f, 0.f, 0.f};

    // ---- GEMM1: gx = X @ W_ih^T  (N=720 as 3 gates x 15 tiles; 16 tile slots) ----
    {
        f32x4 accR[4][2], accZ[4][2], accN[4][2];
        #pragma unroll
        for (int it = 0; it < 4; it++)
            #pragma unroll
            for (int m = 0; m < 2; m++) { accR[it][m] = zero4; accZ[it][m] = zero4; accN[it][m] = zero4; }

        #pragma unroll
        for (int ks = 0; ks < 8; ks++) {
            const int ko = ks*32 + quad*8;
            bf16x8 a0 = *(const bf16x8*)&Xs[l15*XS_STRIDE + ko];
            bf16x8 a1 = *(const bf16x8*)&Xs[(16 + l15)*XS_STRIDE + ko];
            #pragma unroll
            for (int it = 0; it < 4; it++) {
                const int n = (wave + 4*it)*16 + l15;   // t=15 slot: zero-padded rows
                bf16x8 br = *(const bf16x8*)&Wihb[n*256 + ko];
                bf16x8 bz = *(const bf16x8*)&Wihb[(n + 240)*256 + ko];
                bf16x8 bn = *(const bf16x8*)&Wihb[(n + 480)*256 + ko];
                accR[it][0] = MFMA16(a0, br, accR[it][0]);
                accR[it][1] = MFMA16(a1, br, accR[it][1]);
                accZ[it][0] = MFMA16(a0, bz, accZ[it][0]);
                accZ[it][1] = MFMA16(a1, bz, accZ[it][1]);
                accN[it][0] = MFMA16(a0, bn, accN[it][0]);
                accN[it][1] = MFMA16(a1, bn, accN[it][1]);
            }
        }
        // GRU nonlinearity -> Hs (bf16)
        #pragma unroll
        for (int it = 0; it < 4; it++) {
            const int t = wave + 4*it;
            if (t < 15) {
                const int h = t*16 + l15;
                const float add_r = ghb[h],       add_z = ghb[240 + h];
                const float add_n = ghb[480 + h], mul_n = ghb[720 + h];
                const float hi = h_init[h];
                #pragma unroll
                for (int m = 0; m < 2; m++)
                    #pragma unroll
                    for (int r = 0; r < 4; r++) {
                        const int row = m*16 + quad*4 + r;
                        float rg = 1.0f/(1.0f + expf(-(accR[it][m][r] + add_r)));
                        float zg = 1.0f/(1.0f + expf(-(accZ[it][m][r] + add_z)));
                        float ng = tanhf(accN[it][m][r] + add_n + rg*mul_n);
                        Hs[row*XS_STRIDE + h] = __float2bfloat16((1.0f - zg)*ng + zg*hi);
                    }
            }
        }
    }
    __syncthreads();

    // ---- GEMM2: o1 = relu(H @ W_out1^T + b)*mask2  (N=512, 8 tiles/wave) ----
    {
        f32x4 acc2[8][2];
        #pragma unroll
        for (int it = 0; it < 8; it++) { acc2[it][0] = zero4; acc2[it][1] = zero4; }

        #pragma unroll
        for (int ks = 0; ks < 8; ks++) {
            const int ko = ks*32 + quad*8;
            bf16x8 a0 = *(const bf16x8*)&Hs[l15*XS_STRIDE + ko];
            bf16x8 a1 = *(const bf16x8*)&Hs[(16 + l15)*XS_STRIDE + ko];
            #pragma unroll
            for (int it = 0; it < 8; it++) {
                const int n = (wave*8 + it)*16 + l15;
                bf16x8 b = *(const bf16x8*)&Wo1b[n*256 + ko];
                acc2[it][0] = MFMA16(a0, b, acc2[it][0]);
                acc2[it][1] = MFMA16(a1, b, acc2[it][1]);
            }
        }
        const float inv35 = 1.0f/0.35f;
        #pragma unroll
        for (int it = 0; it < 8; it++) {
            const int n = (wave*8 + it)*16 + l15;
            const float bb = b_out1[n];
            #pragma unroll
            for (int m = 0; m < 2; m++)
                #pragma unroll
                for (int r = 0; r < 4; r++) {
                    const int row = m*16 + quad*4 + r;
                    const int b = b0 + row;
                    float uu = u2[((j*B_DIM + b) << 9) + n];
                    float o = fmaxf(acc2[it][m][r] + bb, 0.0f);
                    o = (uu > 0.65f) ? o*inv35 : 0.0f;
                    O1s[row*O1_STRIDE + n] = __float2bfloat16(o);
                }
        }
    }
    __syncthreads();

    // ---- GEMM3: K = o1 @ W_out2^T + b; corr = K.inno; ensemble write ----
    {
        f32x4 acc3[2][2];
        #pragma unroll
        for (int it = 0; it < 2; it++) {
            const int n = (wave*2 + it)*16 + l15;
            const float bo = b_out2[n];
            f32x4 v = {bo, bo, bo, bo};
            acc3[it][0] = v; acc3[it][1] = v;
        }
        #pragma unroll
        for (int ks = 0; ks < 16; ks++) {
            const int ko = ks*32 + quad*8;
            bf16x8 a0 = *(const bf16x8*)&O1s[l15*O1_STRIDE + ko];
            bf16x8 a1 = *(const bf16x8*)&O1s[(16 + l15)*O1_STRIDE + ko];
            #pragma unroll
            for (int it = 0; it < 2; it++) {
                const int n = (wave*2 + it)*16 + l15;
                bf16x8 b = *(const bf16x8*)&Wo2b[n*512 + ko];
                acc3[it][0] = MFMA16(a0, b, acc3[it][0]);
                acc3[it][1] = MFMA16(a1, b, acc3[it][1]);
            }
        }
        #pragma unroll
        for (int it = 0; it < 2; it++) {
            const int n = (wave*2 + it)*16 + l15;
            const int s = n >> 3, o = n & 7;
            #pragma unroll
            for (int m = 0; m < 2; m++)
                #pragma unroll
                for (int r = 0; r < 4; r++) {
                    const int row = m*16 + quad*4 + r;
                    float v = acc3[it][m][r] * InnoS[row*8 + o];
                    v += __shfl_xor(v, 1);
                    v += __shfl_xor(v, 2);
                    v += __shfl_xor(v, 4);
                    if (o == 0)
                        ens[((b0 + row)*J_DIM + j)*16 + s] = XPs[row*16 + s] + v;
                }
        }
    }
}

// ---------------------------------------------------------------------------
// final: mean/var(ddof=1) over J per (b,s) + reg scalar
// ---------------------------------------------------------------------------
__global__ void k_final(const float* __restrict__ ens, float* __restrict__ out)
{
    int t = blockIdx.x * 256 + threadIdx.x;   // 65536 = B*S
    int b = t >> 4, s = t & 15;
    float v[32];
    #pragma unroll
    for (int jj = 0; jj < 32; jj++) v[jj] = ens[(b*32 + jj)*16 + s];
    float m = 0.f;
    #pragma unroll
    for (int jj = 0; jj < 32; jj++) m += v[jj];
    m *= (1.0f/32.0f);
    float var = 0.f;
    #pragma unroll
    for (int jj = 0; jj < 32; jj++) { float d = v[jj] - m; var = fmaf(d, d, var); }
    var *= (1.0f/31.0f);
    out[OUT_X + t] = m;
    out[OUT_P + t] = var;
    if (t == 0) out[OUT_REG] = 1.3405938195945778f;  // ln2 + H(0.65)
}

// ---------------------------------------------------------------------------
extern "C" void kernel_launch(void* const* d_in, const int* in_sizes, int n_in,
                              void* d_out, int out_size, void* d_ws, size_t ws_size,
                              hipStream_t stream)
{
    (void)in_sizes; (void)n_in; (void)out_size; (void)ws_size;
    const float* y_t    = (const float*)d_in[0];
    const float* xprev  = (const float*)d_in[1];
    const float* F      = (const float*)d_in[2];
    const float* Hm     = (const float*)d_in[3];
    const float* Wfc    = (const float*)d_in[4];
    const float* bfc    = (const float*)d_in[5];
    const float* W_ih   = (const float*)d_in[6];
    const float* W_hh   = (const float*)d_in[7];
    const float* b_ih   = (const float*)d_in[8];
    const float* b_hh   = (const float*)d_in[9];
    const float* W_o1   = (const float*)d_in[10];
    const float* b_o1   = (const float*)d_in[11];
    const float* W_o2   = (const float*)d_in[12];
    const float* b_o2   = (const float*)d_in[13];
    const float* h_init = (const float*)d_in[14];
    const float* u1     = (const float*)d_in[15];
    const float* u2     = (const float*)d_in[16];

    float* out = (float*)d_out;
    float* ws  = (float*)d_ws;
    float* x_pred = ws + WS_XPRED;
    float* inno   = ws + WS_INNO;
    float* feats  = ws + WS_FEATS;
    float* x_in0  = ws + WS_XIN0;
    float* ghb    = ws + WS_GH;
    __hip_bfloat16* Wihb = (__hip_bfloat16*)((char*)d_ws + WS_WB_OFF);
    __hip_bfloat16* Wo1b = Wihb + 768*256;
    __hip_bfloat16* Wo2b = Wo1b + 512*256;
    float* ens    = out + OUT_ENS;

    k_aux<<<dim3(1536), dim3(256), 0, stream>>>(W_ih, W_hh, b_ih, b_hh, h_init,
                                                W_o1, W_o2, Wihb, Wo1b, Wo2b, ghb);
    k_pre_a<<<dim3(16), dim3(256), 0, stream>>>(y_t, xprev, F, Hm, x_pred, inno, feats);
    k_pre_b<<<dim3(3840), dim3(256), 0, stream>>>(feats, Wfc, bfc, x_in0);
    k_main<<<dim3(4096), dim3(256), 0, stream>>>(x_in0, u1, u2, Wihb, ghb, h_init,
                                                 Wo1b, b_o1, Wo2b, b_o2,
                                                 x_pred, inno, ens);
    k_final<<<dim3(256), dim3(256), 0, stream>>>(ens, out);
}